// Round 5
// baseline (314.729 us; speedup 1.0000x reference)
//
#include <hip/hip_runtime.h>
#include <stdint.h>

typedef unsigned short ushortT;
typedef __bf16 bf16x8 __attribute__((ext_vector_type(8)));
typedef float f32x16 __attribute__((ext_vector_type(16)));
typedef unsigned short ushort8 __attribute__((ext_vector_type(8)));

#define NPATCH 4096
#define MROWS  131072
#define CFEAT  176
#define KS32   12                      // ksteps of 16 (K padded to 192)
#define T32_BYTES 12288                // one 32-row tile: 12 ks * 64 lanes * 16 B
#define MSPLIT 32                      // 32 chunks x 16 panels = 512 blocks = 2/CU
#define ITER_BYTES 24576               // 2 n-tiles (64 memory rows) per iteration
#define ITERS 64                       // iterations per chunk (2048 total / 32)
#define LROW 180                       // padded LDS row stride (floats)

__device__ __forceinline__ ushortT f2bf(float f) {
    unsigned u = __float_as_uint(f);
    unsigned r = (u + 0x7FFFu + ((u >> 16) & 1u)) >> 16;   // RNE
    return (ushortT)r;
}
__device__ __forceinline__ unsigned f2key(float f) {
    unsigned b = __float_as_uint(f);
    return (b & 0x80000000u) ? ~b : (b | 0x80000000u);     // monotone order-preserving map
}
__device__ __forceinline__ float key2f(unsigned k) {
    return __uint_as_float((k & 0x80000000u) ? (k ^ 0x80000000u) : ~k);
}

// Normalize 64 rows per block; write bf16 in 32x32x16 MFMA fragment order:
// frag[tile][ks][lane][j] = row (tile*32 + lane%32), k = ks*16 + (lane/32)*8 + j (0 if k>=176)
__global__ __launch_bounds__(256) void nrmfrag(const float* __restrict__ in,
                                               ushortT* __restrict__ outfr,
                                               unsigned* __restrict__ keys) {
    __shared__ float buf[64 * LROW];   // 46080 B
    __shared__ float scale[64];
    const int t = threadIdx.x;
    const int row0 = blockIdx.x * 64;

    if (keys != nullptr && t < 64) keys[blockIdx.x * 64 + t] = 0u;

    const float4* g4 = reinterpret_cast<const float4*>(in + (size_t)row0 * CFEAT);
#pragma unroll
    for (int i = 0; i < 11; ++i) {
        const int idx = i * 256 + t;           // 0..2815
        const int row = idx / 44;              // 44 float4 per row
        const int c4  = idx - row * 44;
        float4 v = g4[idx];
        *reinterpret_cast<float4*>(&buf[row * LROW + c4 * 4]) = v;
    }
    __syncthreads();

    {   // norms: 4 threads per row, from LDS
        const int r = t >> 2, part = t & 3;
        const float* rp = &buf[r * LROW + part * 44];
        float s = 0.f;
#pragma unroll
        for (int i = 0; i < 11; ++i) {
            float4 v = *reinterpret_cast<const float4*>(rp + i * 4);
            s += v.x * v.x + v.y * v.y + v.z * v.z + v.w * v.w;
        }
        s += __shfl_xor(s, 1);
        s += __shfl_xor(s, 2);
        if (part == 0) scale[r] = 1.0f / (sqrtf(s) + 1e-6f);
    }
    __syncthreads();

    // pack: wave-pair p handles local tile p (32 rows); each pair member (half)
    // covers ks = half, half+2, ... (6 each)
    const int p = t >> 7;              // local tile 0..1
    const int half = (t >> 6) & 1;
    const int lane = t & 63;
    const int rit = lane & 31;         // row in tile
    const int kh = lane >> 5;
    const int lrow = p * 32 + rit;
    const float* rp = &buf[lrow * LROW];
    const float sc = scale[lrow];
    const size_t tile = (size_t)blockIdx.x * 2 + p;
#pragma unroll
    for (int i = 0; i < 6; ++i) {
        const int ks = half + 2 * i;
        const int kb = ks * 16 + kh * 8;
        ushort8 o;
        if (kb < CFEAT) {  // 8-groups fully in-range (kb<=168 -> kb+8<=176) or fully pad
            float4 v0 = *reinterpret_cast<const float4*>(rp + kb);
            float4 v1 = *reinterpret_cast<const float4*>(rp + kb + 4);
            o[0] = f2bf(v0.x * sc); o[1] = f2bf(v0.y * sc);
            o[2] = f2bf(v0.z * sc); o[3] = f2bf(v0.w * sc);
            o[4] = f2bf(v1.x * sc); o[5] = f2bf(v1.y * sc);
            o[6] = f2bf(v1.z * sc); o[7] = f2bf(v1.w * sc);
        } else {
#pragma unroll
            for (int j = 0; j < 8; ++j) o[j] = 0;
        }
        *reinterpret_cast<ushort8*>(outfr + (tile * KS32 + ks) * (size_t)512 + lane * 8) = o;
    }
}

// Max-reduced GEMM, 32x32x16 MFMA (2495 TF shape ceiling vs 2176 for 16x16x32).
// Schedule = round-2 proven optimum: stage-first, compute, vmcnt(0) + raw barrier.
__global__ __launch_bounds__(256, 2) void gemm_max(const ushortT* __restrict__ pfr,
                                                   const ushortT* __restrict__ mfr,
                                                   unsigned* __restrict__ keys) {
    __shared__ ushortT lds[2][ITER_BYTES / 2];   // 49152 B
    const int t = threadIdx.x;
    const int w = t >> 6;
    const int lane = t & 63;
    const int mchunk = blockIdx.x;
    const int panel = blockIdx.y;

    const int itb = mchunk * ITERS;
    const int ite = itb + ITERS;

    // A fragments: 2 m-tiles (64 patch rows) x 12 ksteps, registers for whole kernel
    bf16x8 a[2][KS32];
    {
        const int ptile0 = panel * 8 + w * 2;
#pragma unroll
        for (int m = 0; m < 2; ++m)
#pragma unroll
            for (int k = 0; k < KS32; ++k)
                a[m][k] = *reinterpret_cast<const bf16x8*>(
                    pfr + ((size_t)(ptile0 + m) * KS32 + k) * 512 + lane * 8);
    }

    float runmax[2][16];
#pragma unroll
    for (int m = 0; m < 2; ++m)
#pragma unroll
        for (int r = 0; r < 16; ++r) runmax[m][r] = -3.0e38f;

    const uint8_t* gb = reinterpret_cast<const uint8_t*>(mfr);

    auto stage = [&](int buf, int it) {   // it = global iter index
        const uint8_t* src = gb + (size_t)it * ITER_BYTES + w * 6144 + lane * 16;
        uint8_t* dstb = reinterpret_cast<uint8_t*>(&lds[buf][0]) + w * 6144;
#pragma unroll
        for (int i = 0; i < 6; ++i) {
            __builtin_amdgcn_global_load_lds(
                (const __attribute__((address_space(1))) unsigned int*)(src + i * 1024),
                (__attribute__((address_space(3))) unsigned int*)(dstb + i * 1024),
                16, 0, 0);
        }
    };

    stage(0, itb);
    asm volatile("s_waitcnt vmcnt(0)" ::: "memory");
    __builtin_amdgcn_s_barrier();

    int cur = 0;
    for (int it = itb; it < ite; ++it) {
        if (it + 1 < ite) stage(cur ^ 1, it + 1);   // issue prefetch FIRST

        const ushortT* lb = &lds[cur][0];
#pragma unroll
        for (int n = 0; n < 2; ++n) {
            bf16x8 b[KS32];
#pragma unroll
            for (int k = 0; k < KS32; ++k)
                b[k] = *reinterpret_cast<const bf16x8*>(lb + (n * KS32 + k) * 512 + lane * 8);
            f32x16 acc[2];
#pragma unroll
            for (int m = 0; m < 2; ++m)
#pragma unroll
                for (int r = 0; r < 16; ++r) acc[m][r] = 0.f;
#pragma unroll
            for (int k = 0; k < KS32; ++k)
#pragma unroll
                for (int m = 0; m < 2; ++m)
                    acc[m] = __builtin_amdgcn_mfma_f32_32x32x16_bf16(a[m][k], b[k], acc[m], 0, 0, 0);
#pragma unroll
            for (int m = 0; m < 2; ++m)
#pragma unroll
                for (int r = 0; r < 16; ++r)
                    runmax[m][r] = fmaxf(runmax[m][r], acc[m][r]);
        }

        asm volatile("s_waitcnt vmcnt(0)" ::: "memory");
        __builtin_amdgcn_s_barrier();
        cur ^= 1;
    }

    // C/D layout (HW-verified): col=lane&31 (memory row), row=(r&3)+8*(r>>2)+4*(lane>>5).
    // Max over memory rows = reduce over lane&31; lanes 0 and 32 hold results.
#pragma unroll
    for (int m = 0; m < 2; ++m) {
#pragma unroll
        for (int r = 0; r < 16; ++r) {
            float v = runmax[m][r];
            v = fmaxf(v, __shfl_xor(v, 1));
            v = fmaxf(v, __shfl_xor(v, 2));
            v = fmaxf(v, __shfl_xor(v, 4));
            v = fmaxf(v, __shfl_xor(v, 8));
            v = fmaxf(v, __shfl_xor(v, 16));
            if ((lane & 31) == 0) {
                int rowInTile = (r & 3) + 8 * (r >> 2) + 4 * (lane >> 5);
                int prow = panel * 256 + w * 64 + m * 32 + rowInTile;
                atomicMax(&keys[prow], f2key(v));
            }
        }
    }
}

// decode keys -> patch scores; iterative top-k (k from device) -> mean
__global__ __launch_bounds__(256) void finalize(const unsigned* __restrict__ keys,
                                                const int* __restrict__ topk_p,
                                                float* __restrict__ out) {
    __shared__ float s[NPATCH];
    __shared__ float rv[256];
    __shared__ int ri[256];
    const int t = threadIdx.x;
    for (int i = t; i < NPATCH; i += 256) {
        float score = 1.0f - key2f(keys[i]);
        out[i] = score;
        s[i] = score;
    }
    __syncthreads();
    const int K = *topk_p;
    float sum = 0.f;
    for (int it = 0; it < K; ++it) {
        float bv = -3.0e38f; int bi = -1;
        for (int i = t; i < NPATCH; i += 256)
            if (s[i] > bv) { bv = s[i]; bi = i; }
        rv[t] = bv; ri[t] = bi;
        __syncthreads();
        for (int off = 128; off > 0; off >>= 1) {
            if (t < off && rv[t + off] > rv[t]) { rv[t] = rv[t + off]; ri[t] = ri[t + off]; }
            __syncthreads();
        }
        if (t == 0) { sum += rv[0]; s[ri[0]] = -3.0e38f; }
        __syncthreads();
    }
    if (t == 0) out[NPATCH] = sum / (float)K;
}

extern "C" void kernel_launch(void* const* d_in, const int* in_sizes, int n_in,
                              void* d_out, int out_size, void* d_ws, size_t ws_size,
                              hipStream_t stream) {
    (void)in_sizes; (void)n_in; (void)out_size; (void)ws_size;
    const float* patch = (const float*)d_in[0];
    const float* mem   = (const float*)d_in[1];
    const int*   topk  = (const int*)d_in[2];
    float* out = (float*)d_out;

    uint8_t* ws = (uint8_t*)d_ws;
    ushortT*  mfr  = (ushortT*)ws;                                   // 50,331,648 B
    ushortT*  pfr  = (ushortT*)(ws + 50331648);                      //  1,572,864 B
    unsigned* keys = (unsigned*)(ws + 50331648 + 1572864);           //     16,384 B

    nrmfrag<<<MROWS / 64, 256, 0, stream>>>(mem, mfr, nullptr);
    nrmfrag<<<NPATCH / 64, 256, 0, stream>>>(patch, pfr, keys);     // also zeroes keys
    gemm_max<<<dim3(MSPLIT, 16), 256, 0, stream>>>(pfr, mfr, keys);
    finalize<<<1, 256, 0, stream>>>(keys, topk, out);
}